// Round 3
// baseline (4498.358 us; speedup 1.0000x reference)
//
#include <hip/hip_runtime.h>
#include <hip/hip_bf16.h>
#include <stdint.h>

typedef __attribute__((ext_vector_type(4))) float f32x4;
typedef __attribute__((ext_vector_type(8))) short bf16x8;
typedef __attribute__((ext_vector_type(8))) unsigned short us8;
typedef unsigned short u16;
typedef unsigned int u32;

#define DEV static __device__ __forceinline__

DEV u16 f2b(float f){
  u32 u = __float_as_uint(f);
  u += 0x7fffu + ((u >> 16) & 1u);
  return (u16)(u >> 16);
}
DEV float b2f(u16 h){ return __uint_as_float(((u32)h) << 16); }

// ---------------- pad & cast x : xp[b][s+3][d] = bf16(x[b][s][d]), 3 zero rows each side ----------------
__global__ void k_pad_cast(const float* __restrict__ x, u16* __restrict__ xp){
  int i8 = blockIdx.x * blockDim.x + threadIdx.x;      // one 8-elem chunk
  int d8 = i8 % 96; int rest = i8 / 96;
  int sp = rest % 262; int b = rest / 262;
  us8 o;
  int s = sp - 3;
  if (s >= 0 && s < 256){
    const float* src = x + ((long)(b*256 + s)*768 + d8*8);
    #pragma unroll
    for (int j=0;j<8;j++) o[j] = f2b(src[j]);
  } else {
    #pragma unroll
    for (int j=0;j<8;j++) o[j] = 0;
  }
  *(us8*)(xp + (long)i8*8) = o;
}

// ---------------- V[d][c][i] f32: zero-padded per-tap conv weights ----------------
// d<7 (offset d-3), c<768 (concat channel), i<768 (input dim)
__global__ void k_build_v(const float* __restrict__ cw3, const float* __restrict__ cw5,
                          const float* __restrict__ cw7, float* __restrict__ V){
  int idx = blockIdx.x * blockDim.x + threadIdx.x;
  if (idx >= 7*768*768) return;
  int d = idx / (768*768); int rem = idx - d*(768*768);
  int c = rem / 768; int i = rem - c*768;
  int dd = d - 3;
  float v = 0.f;
  if (c < 256){ int t = dd + 1; if (t >= 0 && t < 3) v = cw3[((long)c*768 + i)*3 + t]; }
  else if (c < 512){ int t = dd + 2; if (t >= 0 && t < 5) v = cw5[((long)(c-256)*768 + i)*5 + t]; }
  else { int t = dd + 3; v = cw7[((long)(c-512)*768 + i)*7 + t]; }
  V[idx] = v;
}

// ---------------- Weff_bt[j][d*768+i] = sum_c Wx_cat[j][c] * V[d][c][i]  (f32 compute, bf16 out) ----------------
__global__ __launch_bounds__(256) void k_weff(
    const float* __restrict__ wxrz, const float* __restrict__ wxn,
    const float* __restrict__ V, u16* __restrict__ wt)
{
  __shared__ float As[16][64];
  __shared__ float Bs[16][64];
  const int t = threadIdx.x;
  const int it = blockIdx.x, jt = blockIdx.y, dlt = blockIdx.z;
  const float* Arow = (jt < 12) ? (wxrz + (long)jt*64*768) : (wxn + (long)(jt-12)*64*768);
  const int tx = t & 15, ty = t >> 4;
  const int jA = t >> 2, cqA = (t & 3) * 4;
  const int iB = t & 63, cB = t >> 6;
  float acc[4][4] = {};
  for (int k0 = 0; k0 < 768; k0 += 16){
    __syncthreads();
    float4 av = *(const float4*)(Arow + (long)jA*768 + k0 + cqA);
    As[cqA+0][jA] = av.x; As[cqA+1][jA] = av.y; As[cqA+2][jA] = av.z; As[cqA+3][jA] = av.w;
    #pragma unroll
    for (int l=0;l<4;l++){
      int c = cB + l*4;
      Bs[c][iB] = V[((long)dlt*768 + k0 + c)*768 + it*64 + iB];
    }
    __syncthreads();
    #pragma unroll
    for (int kk=0;kk<16;kk++){
      float4 a4 = *(const float4*)(&As[kk][ty*4]);
      float4 b4 = *(const float4*)(&Bs[kk][tx*4]);
      float aa[4] = {a4.x,a4.y,a4.z,a4.w}, bb[4] = {b4.x,b4.y,b4.z,b4.w};
      #pragma unroll
      for (int jj=0;jj<4;jj++)
        #pragma unroll
        for (int ii=0;ii<4;ii++) acc[jj][ii] += aa[jj]*bb[ii];
    }
  }
  #pragma unroll
  for (int jj=0;jj<4;jj++){
    long j = jt*64 + ty*4 + jj;
    #pragma unroll
    for (int ii=0;ii<4;ii++){
      int i = it*64 + tx*4 + ii;
      wt[j*5376 + dlt*768 + i] = f2b(acc[jj][ii]);
    }
  }
}

// ---------------- beff[j] = Wx_b[j] + sum_c Wx[j][c]*conv_b_cat[c] ----------------
__global__ void k_beff(const float* __restrict__ wxrz, const float* __restrict__ wxn,
                       const float* __restrict__ bxrz, const float* __restrict__ bxn,
                       const float* __restrict__ cb3, const float* __restrict__ cb5,
                       const float* __restrict__ cb7, float* __restrict__ beff){
  int j = blockIdx.x*blockDim.x + threadIdx.x;
  if (j >= 1152) return;
  const float* row = (j < 768) ? (wxrz + (long)j*768) : (wxn + (long)(j-768)*768);
  float s = (j < 768) ? bxrz[j] : bxn[j-768];
  for (int c=0;c<768;c++){
    float cb = (c<256) ? cb3[c] : (c<512) ? cb5[c-256] : cb7[c-512];
    s += row[c]*cb;
  }
  beff[j] = s;
}

// ---------------- pack [Whrz] as w4[kg][col][u] = W[col][kg*4+u] (bf16, r/z gates) + bias(1152) ----------------
__global__ void k_pack_wh4(const float* __restrict__ whrz, const float* __restrict__ whn,
                           const float* __restrict__ bhrz, const float* __restrict__ bhn,
                           u16* __restrict__ w4, float* __restrict__ bias){
  int idx = blockIdx.x * blockDim.x + threadIdx.x;
  if (idx < 96*1152*4){
    int u = idx & 3;
    int cg = idx >> 2;
    int col = cg % 1152;
    int kg = cg / 1152;
    int kk = kg*4 + u;
    float v = (col < 768) ? whrz[(long)col*384 + kk] : whn[(long)(col-768)*384 + kk];
    w4[idx] = f2b(v);
  }
  if (idx < 1152) bias[idx] = (idx < 768) ? bhrz[idx] : bhn[idx-768];
}

// ---------------- pack Whn as f32: wn[kg][t][u] = whn[t][kg*4+u] ----------------
__global__ void k_pack_whn(const float* __restrict__ whn, float* __restrict__ wn){
  int idx = blockIdx.x*blockDim.x + threadIdx.x;
  if (idx >= 96*384*4) return;
  int u = idx & 3; int cg = idx >> 2; int t = cg % 384; int kg = cg / 384;
  wn[idx] = whn[(long)t*384 + kg*4 + u];
}

// ---------------- bf16 GEMM, m97 structure: C[r][c] = sum_k A[r][k]*Bt[c][k] (+bias[c]) ----------------
// A rows: base = (r>>8)*a_sb + (r&255)*a_ss (elements). M-tiles (128) never cross a 256-row batch.
template<bool F32OUT>
__global__ __launch_bounds__(256) void k_gemm(
    const u16* __restrict__ A, long a_sb, long a_ss,
    const u16* __restrict__ Bt, int K,
    const float* __restrict__ bias,
    void* __restrict__ C, int ldc, int col0)
{
  __shared__ __align__(16) u16 As[128*64];
  __shared__ __align__(16) u16 Bs[128*64];
  const int tid = threadIdx.x;
  const int wave = tid >> 6, lane = tid & 63;
  const int mt = blockIdx.x, nt = blockIdx.y;
  const long abase = (long)(mt >> 1)*a_sb + (long)((mt & 1)*128)*a_ss;
  const long bbase = (long)nt*128*K;
  const int lr = lane >> 3;            // row within 8-row group
  const int lc = (lane & 7) * 8;       // elem col within 64
  const int wr = (wave >> 1)*64, wc = (wave & 1)*64;

  f32x4 acc[4][4];
  #pragma unroll
  for (int mi=0;mi<4;mi++)
    #pragma unroll
    for (int ni=0;ni<4;ni++) acc[mi][ni] = 0;

  for (int k0 = 0; k0 < K; k0 += 64){
    __syncthreads();
    #pragma unroll
    for (int a=0;a<4;a++){
      int q = wave*4 + a;
      const u16* srcA = A + abase + (long)(q*8 + lr)*a_ss + k0 + lc;
      __builtin_amdgcn_global_load_lds((const __attribute__((address_space(1))) void*)srcA,
                                       (__attribute__((address_space(3))) void*)(As + q*8*64), 16, 0, 0);
      const u16* srcB = Bt + bbase + (long)(q*8 + lr)*K + k0 + lc;
      __builtin_amdgcn_global_load_lds((const __attribute__((address_space(1))) void*)srcB,
                                       (__attribute__((address_space(3))) void*)(Bs + q*8*64), 16, 0, 0);
    }
    __syncthreads();
    #pragma unroll
    for (int kk=0;kk<2;kk++){
      const int kb = kk*32 + (lane >> 4)*8;
      bf16x8 af[4], bfr[4];
      #pragma unroll
      for (int mi=0;mi<4;mi++)
        af[mi] = *(const bf16x8*)(As + (wr + mi*16 + (lane & 15))*64 + kb);
      #pragma unroll
      for (int ni=0;ni<4;ni++)
        bfr[ni] = *(const bf16x8*)(Bs + (wc + ni*16 + (lane & 15))*64 + kb);
      #pragma unroll
      for (int mi=0;mi<4;mi++)
        #pragma unroll
        for (int ni=0;ni<4;ni++)
          acc[mi][ni] = __builtin_amdgcn_mfma_f32_16x16x32_bf16(af[mi], bfr[ni], acc[mi][ni], 0, 0, 0);
    }
  }
  const int rbase = mt*128 + wr + ((lane >> 4) << 2);
  const int cbase = nt*128 + wc + (lane & 15);
  #pragma unroll
  for (int mi=0;mi<4;mi++){
    #pragma unroll
    for (int ni=0;ni<4;ni++){
      int col = cbase + ni*16;
      float bv = bias ? bias[col] : 0.0f;
      #pragma unroll
      for (int j=0;j<4;j++){
        int row = rbase + mi*16 + j;
        if (F32OUT) ((float*)C)[(long)row*ldc + col0 + col] = acc[mi][ni][j] + bv;
        else        ((u16*)C)[(long)row*ldc + col0 + col] = f2b(acc[mi][ni][j] + bv);
      }
    }
  }
}

// ---------------- row LN on f32 scores (in-place): seg [0,768) w/ lnx1, [768,1152) w/ lnx2 ----------------
__global__ __launch_bounds__(192) void k_ln1(
    float* __restrict__ sc,
    const float* __restrict__ g1, const float* __restrict__ b1,
    const float* __restrict__ g2, const float* __restrict__ b2)
{
  long row = blockIdx.x;
  float* r = sc + row*1152;
  int t = threadIdx.x;
  __shared__ float red[3][4];
  float s0=0, q0=0, s1=0, q1=0;
  float4 va, vb;
  if (t < 144){
    va = *(const float4*)(r + t*8);
    vb = *(const float4*)(r + t*8 + 4);
    float a = va.x+va.y+va.z+va.w + vb.x+vb.y+vb.z+vb.w;
    float aq = va.x*va.x+va.y*va.y+va.z*va.z+va.w*va.w
             + vb.x*vb.x+vb.y*vb.y+vb.z*vb.z+vb.w*vb.w;
    if (t < 96){ s0 = a; q0 = aq; } else { s1 = a; q1 = aq; }
  }
  int lane = t & 63, wid = t >> 6;
  #pragma unroll
  for (int o=32;o>0;o>>=1){
    s0 += __shfl_down(s0,o); q0 += __shfl_down(q0,o);
    s1 += __shfl_down(s1,o); q1 += __shfl_down(q1,o);
  }
  if (lane == 0){ red[wid][0]=s0; red[wid][1]=q0; red[wid][2]=s1; red[wid][3]=q1; }
  __syncthreads();
  float S0 = red[0][0]+red[1][0]+red[2][0];
  float Q0 = red[0][1]+red[1][1]+red[2][1];
  float S1 = red[0][2]+red[1][2]+red[2][2];
  float Q1 = red[0][3]+red[1][3]+red[2][3];
  if (t < 144){
    float mu, rs; const float *g, *bb; int cb;
    if (t < 96){ mu = S0*(1.f/768.f); rs = rsqrtf(Q0*(1.f/768.f) - mu*mu + 1e-5f); g=g1; bb=b1; cb = t*8; }
    else       { mu = S1*(1.f/384.f); rs = rsqrtf(Q1*(1.f/384.f) - mu*mu + 1e-5f); g=g2; bb=b2; cb = (t-96)*8; }
    float o[8] = {va.x,va.y,va.z,va.w,vb.x,vb.y,vb.z,vb.w};
    #pragma unroll
    for (int j=0;j<8;j++) o[j] = (o[j] - mu)*rs*g[cb+j] + bb[cb+j];
    *(float4*)(r + t*8)     = make_float4(o[0],o[1],o[2],o[3]);
    *(float4*)(r + t*8 + 4) = make_float4(o[4],o[5],o[6],o[7]);
  }
}

// ---------------- BiGRU: one block per (batch, dir); f32 h; bf16 Whrz + f32 Whn streamed ----------------
__global__ __launch_bounds__(384) void k_gru(
    const float* __restrict__ a,  // (32768 x 1152) [arz | an], f32
    const u16* __restrict__ W4,   // (96 x 1152 x 4) bf16 (cols 0..767 = r,z used)
    const float* __restrict__ Wn, // (96 x 384 x 4) f32
    const float* __restrict__ bh, // 1152 = [Whrz_b | Whn_b]
    const float* __restrict__ g1, const float* __restrict__ b1,  // lnh1 (768)
    const float* __restrict__ g2, const float* __restrict__ b2,  // lnh2 (384)
    float* __restrict__ outr)     // (32768 x 768) [fwd | bwd], f32
{
  const int bd = blockIdx.x;
  const int b = bd & 127, dir = bd >> 7;
  const int t = threadIdx.x;
  const int lane = t & 63, wid = t >> 6;
  __shared__ __align__(16) float h[384];
  __shared__ float red[6][4];
  h[t] = 0.f;
  const float G1r = g1[t], B1r = b1[t], G1z = g1[t+384], B1z = b1[t+384], G2 = g2[t], B2 = b2[t];
  const float bh0 = bh[t], bh1 = bh[t+384], bh2 = bh[t+768];
  __syncthreads();
  for (int step=0; step<256; step++){
    int s = dir ? (255-step) : step;
    const float* arow = a + ((long)(b*256 + s))*1152;
    float acc0 = bh0, acc1 = bh1, acc2 = bh2;
    for (int kg=0; kg<96; kg++){
      float4 hv = *(const float4*)(h + kg*4);
      const u16* wp = W4 + ((long)kg*1152 + t)*4;
      ushort4 w0 = *(const ushort4*)(wp);
      ushort4 w1 = *(const ushort4*)(wp + 1536);
      float4  wn = *(const float4*)(Wn + ((long)kg*384 + t)*4);
      acc0 += b2f(w0.x)*hv.x + b2f(w0.y)*hv.y + b2f(w0.z)*hv.z + b2f(w0.w)*hv.w;
      acc1 += b2f(w1.x)*hv.x + b2f(w1.y)*hv.y + b2f(w1.z)*hv.z + b2f(w1.w)*hv.w;
      acc2 += wn.x*hv.x + wn.y*hv.y + wn.z*hv.z + wn.w*hv.w;
    }
    float s1v = acc0 + acc1, q1v = acc0*acc0 + acc1*acc1, s2v = acc2, q2v = acc2*acc2;
    #pragma unroll
    for (int o=32;o>0;o>>=1){
      s1v += __shfl_down(s1v,o); q1v += __shfl_down(q1v,o);
      s2v += __shfl_down(s2v,o); q2v += __shfl_down(q2v,o);
    }
    if (lane == 0){ red[wid][0]=s1v; red[wid][1]=q1v; red[wid][2]=s2v; red[wid][3]=q2v; }
    __syncthreads();   // matvec h-reads complete before this; red ready after
    float S1=0, Q1=0, S2=0, Q2=0;
    #pragma unroll
    for (int w=0; w<6; w++){ S1+=red[w][0]; Q1+=red[w][1]; S2+=red[w][2]; Q2+=red[w][3]; }
    float mu1 = S1*(1.f/768.f), rs1 = rsqrtf(Q1*(1.f/768.f) - mu1*mu1 + 1e-5f);
    float mu2 = S2*(1.f/384.f), rs2 = rsqrtf(Q2*(1.f/384.f) - mu2*mu2 + 1e-5f);
    float arz_r = arow[t], arz_z = arow[t+384], an = arow[t+768];
    float gr = 1.f/(1.f + __expf(-(arz_r + (acc0-mu1)*rs1*G1r + B1r)));
    float gz = 1.f/(1.f + __expf(-(arz_z + (acc1-mu1)*rs1*G1z + B1z)));
    float nln = (acc2-mu2)*rs2*G2 + B2;
    float n = tanhf(an + gr*nln);
    float hn = (1.f-gz)*n + gz*h[t];
    h[t] = hn;
    outr[((long)(b*256+s))*768 + dir*384 + t] = hn;
    __syncthreads();  // h ready & protected before next step
  }
}

// ---------------- final LN over 768 (f32 in), f32 out ----------------
__global__ __launch_bounds__(128) void k_lnout(
    const float* __restrict__ hr, const float* __restrict__ g, const float* __restrict__ bb,
    float* __restrict__ out)
{
  long row = blockIdx.x;
  const float* r = hr + row*768;
  int t = threadIdx.x;
  __shared__ float red[2][2];
  float s=0, q=0;
  float4 va, vb;
  if (t < 96){
    va = *(const float4*)(r + t*8);
    vb = *(const float4*)(r + t*8 + 4);
    s = va.x+va.y+va.z+va.w + vb.x+vb.y+vb.z+vb.w;
    q = va.x*va.x+va.y*va.y+va.z*va.z+va.w*va.w
      + vb.x*vb.x+vb.y*vb.y+vb.z*vb.z+vb.w*vb.w;
  }
  int lane = t & 63, wid = t >> 6;
  #pragma unroll
  for (int o=32;o>0;o>>=1){ s += __shfl_down(s,o); q += __shfl_down(q,o); }
  if (lane == 0){ red[wid][0]=s; red[wid][1]=q; }
  __syncthreads();
  float S = red[0][0]+red[1][0], Q = red[0][1]+red[1][1];
  float mu = S*(1.f/768.f), rs = rsqrtf(Q*(1.f/768.f) - mu*mu + 1e-5f);
  if (t < 96){
    float* op = out + row*768 + t*8;
    float iv[8] = {va.x,va.y,va.z,va.w,vb.x,vb.y,vb.z,vb.w};
    #pragma unroll
    for (int j=0;j<8;j++) op[j] = (iv[j] - mu)*rs*g[t*8+j] + bb[t*8+j];
  }
}

extern "C" void kernel_launch(void* const* d_in, const int* in_sizes, int n_in,
                              void* d_out, int out_size, void* d_ws, size_t ws_size,
                              hipStream_t stream){
  const float* x     = (const float*)d_in[0];
  const float* cw3   = (const float*)d_in[1];
  const float* cb3   = (const float*)d_in[2];
  const float* cw5   = (const float*)d_in[3];
  const float* cb5   = (const float*)d_in[4];
  const float* cw7   = (const float*)d_in[5];
  const float* cb7   = (const float*)d_in[6];
  const float* wxrz  = (const float*)d_in[7];
  const float* bxrz  = (const float*)d_in[8];
  const float* whrz  = (const float*)d_in[9];
  const float* bhrz  = (const float*)d_in[10];
  const float* wxn   = (const float*)d_in[11];
  const float* bxn   = (const float*)d_in[12];
  const float* whn   = (const float*)d_in[13];
  const float* bhn   = (const float*)d_in[14];
  const float* lnx1g = (const float*)d_in[15];
  const float* lnx1b = (const float*)d_in[16];
  const float* lnh1g = (const float*)d_in[17];
  const float* lnh1b = (const float*)d_in[18];
  const float* lnx2g = (const float*)d_in[19];
  const float* lnx2b = (const float*)d_in[20];
  const float* lnh2g = (const float*)d_in[21];
  const float* lnh2b = (const float*)d_in[22];
  const float* lnog  = (const float*)d_in[23];
  const float* lnob  = (const float*)d_in[24];

  char* w = (char*)d_ws;
  auto alloc = [&](size_t bytes)->char*{ char* p = w; w += (bytes + 255) & ~(size_t)255; return p; };
  // persistent (live through k_gru):
  float* sc  = (float*)alloc(32768L*1152*4);   // 151 MB f32 scores -> a (in-place LN)
  u16*  w4   = (u16*) alloc(96L*1152*4*2);
  float* wnf = (float*)alloc(96L*384*4*4);
  float* bhp = (float*)alloc(1152*4);
  // transient (dead after main GEMM) — outr aliases from regionA start:
  char* regionA = w;
  u16*  xp   = (u16*) alloc(128L*262*768*2);   // 51.5 MB padded bf16 x
  u16*  weff = (u16*) alloc(1152L*5376*2);     // 12.4 MB
  float* V   = (float*)alloc(7L*768*768*4);    // 16.5 MB
  float* beff= (float*)alloc(1152*4);
  float* outr = (float*)regionA;               // 100.7 MB (transients 80.4MB + fresh tail)

  k_pad_cast<<<12576, 256, 0, stream>>>(x, xp);
  k_build_v<<<16128, 256, 0, stream>>>(cw3, cw5, cw7, V);
  k_weff<<<dim3(12,18,7), 256, 0, stream>>>(wxrz, wxn, V, weff);
  k_beff<<<5, 256, 0, stream>>>(wxrz, wxn, bxrz, bxn, cb3, cb5, cb7, beff);
  k_pack_wh4<<<1728, 256, 0, stream>>>(whrz, whn, bhrz, bhn, w4, bhp);
  k_pack_whn<<<576, 256, 0, stream>>>(whn, wnf);

  // a = LN(x_pad (*) Weff + beff): one fused GEMM, M=32768 N=1152 K=5376
  k_gemm<true><<<dim3(256,9), 256, 0, stream>>>(xp, 262L*768, 768, weff, 5376, beff, sc, 1152, 0);
  k_ln1<<<32768, 192, 0, stream>>>(sc, lnx1g, lnx1b, lnx2g, lnx2b);
  k_gru<<<256, 384, 0, stream>>>(sc, w4, wnf, bhp, lnh1g, lnh1b, lnh2g, lnh2b, outr);
  k_lnout<<<32768, 128, 0, stream>>>(outr, lnog, lnob, (float*)d_out);
}